// Round 12
// baseline (20.910 us; speedup 1.0000x reference)
//
#include <hip/hip_runtime.h>
#include <math.h>

// DMLoss fused kernel for MI355X (gfx950).
// Round 12: in-wave DPP argmin. R3/R9/R11 plateau at ~19us across 4x scan-LDS
// reduction -> phase/merge/barrier structure binds, not issue throughput.
// New layout: group g=tid>>4 owns 4 points; lane h=tid&15 scans strided
// segment slice {h, h+16, ...} (<=2-way LDS bank alias = free). Argmin merge =
// 4-step row_ror DPP butterfly on packed u64 (d_bits<<32 | idx): pure VALU,
// exact first-occurrence semantics, zero LDS, zero barriers. 2 barriers total;
// leaders (h==0) write block sums directly. Two-kernel structure (no ticket).

#define BB 1024
#define NN 128
#define MM 128

typedef unsigned long long u64;

__device__ __forceinline__ float sl1(float x) {
    float d = fabsf(x);
    return d < 1.0f ? 0.5f * d * d : d - 0.5f;
}

// One butterfly step of u64-min across a 16-lane DPP row. CTRL = 0x120|N (row_ror:N).
template <int CTRL>
__device__ __forceinline__ u64 dpp_min_step(u64 best) {
    unsigned lo = (unsigned)best, hi = (unsigned)(best >> 32);
    unsigned lo2 = (unsigned)__builtin_amdgcn_mov_dpp((int)lo, CTRL, 0xf, 0xf, false);
    unsigned hi2 = (unsigned)__builtin_amdgcn_mov_dpp((int)hi, CTRL, 0xf, 0xf, false);
    u64 o = ((u64)hi2 << 32) | lo2;
    return o < best ? o : best;
}

__device__ __forceinline__ u64 dpp_min16(u64 best) {
    best = dpp_min_step<0x128>(best);   // ror:8
    best = dpp_min_step<0x124>(best);   // ror:4
    best = dpp_min_step<0x122>(best);   // ror:2
    best = dpp_min_step<0x121>(best);   // ror:1
    return best;
}

__global__ void __launch_bounds__(512, 4)
dmloss_main(const float* __restrict__ ini, const float* __restrict__ pred,
            const float* __restrict__ gt,  const float* __restrict__ kmask,
            float4* __restrict__ partials)
{
    const int b   = blockIdx.x;
    const int tid = threadIdx.x;
    const int g   = tid >> 4;    // 0..31: owns points {4g .. 4g+3}
    const int h   = tid & 15;    // scan lane within the 16-lane DPP row

    __shared__ __align__(16) float2 s_gt[MM];    // raw gt points
    __shared__ __align__(16) float2 s_pr[NN];    // pred points
    __shared__ __align__(16) float2 s_ii[NN];    // ini points
    __shared__ float4 s_segA[MM];                // (ax, ay, Xn, Yn)
    __shared__ float2 s_segB[MM];                // (ex/10, ey/10)
    __shared__ __align__(16) float s_km[NN];     // keypoint mask
    __shared__ float  s_step[16];                // exact j/10
    __shared__ float  s_sum[3][32];              // per-group partial sums

    const float2* gt2 = (const float2*)(gt   + (size_t)b * MM * 2);
    const float2* in2 = (const float2*)(ini  + (size_t)b * NN * 2);
    const float2* pr2 = (const float2*)(pred + (size_t)b * NN * 2);

    // ---- staging (single barrier) ----
    if (tid < 128) {
        int m = tid;
        float2 gm = gt2[m];
        float2 a  = gt2[(m + 127) & 127];
        s_gt[m] = gm;
        float ex = gm.x - a.x, ey = gm.y - a.y;
        float A  = ex * ex + ey * ey;
        float inv = A > 0.f ? 10.f / A : 0.f;   // degenerate seg -> vertex 0
        s_segA[m] = make_float4(a.x, a.y, -ex * inv, -ey * inv);
        s_segB[m] = make_float2(ex * 0.1f, ey * 0.1f);
        if (tid < 16) s_step[tid] = (float)tid / 10.0f;
    } else if (tid < 256) {
        s_pr[tid - 128] = pr2[tid - 128];
    } else if (tid < 384) {
        s_ii[tid - 256] = in2[tid - 256];
    } else {
        s_km[tid - 384] = kmask[b * MM + (tid - 384)];
    }

    // Own ini points {4g..4g+3} (group-uniform; L1 broadcasts the line).
    float4 pv0 = *(const float4*)(&in2[4 * g]);
    float4 pv1 = *(const float4*)(&in2[4 * g + 2]);
    __syncthreads();

    // ---- Phase B scan: 4 points vs strided segment slice {h, h+16, ...} ----
    // Segment m: a=gt[m-1], e=gt[m]-a, q=a-p; jv=qx*Xn+qy*Yn (Xn=-ex*10/|e|^2);
    // jr=rint(med3(jv,0,9)); d=|q+(e/10)*jr|^2; candidate key = (d_bits<<32)|idx.
    u64 B0 = ~0ull, B1 = ~0ull, B2 = ~0ull, B3 = ~0ull;
    #pragma unroll
    for (int j = 0; j < 8; ++j) {
        const int m = h + 16 * j;
        float4 SA = s_segA[m];          // <=2-way bank alias: free
        float2 SB = s_segB[m];          // conflict-free
        const int base = 10 * m;
        #define CANDB(px, py, bb)                                            \
        {                                                                    \
            float qx = SA.x - (px), qy = SA.y - (py);                        \
            float jv = fmaf(qy, SA.w, qx * SA.z);                            \
            float jr = rintf(__builtin_amdgcn_fmed3f(jv, 0.f, 9.f));         \
            float dx = fmaf(jr, SB.x, qx);                                   \
            float dy = fmaf(jr, SB.y, qy);                                   \
            float d  = fmaf(dy, dy, dx * dx);                                \
            u64 c = ((u64)__builtin_bit_cast(unsigned, d) << 32)             \
                    | (unsigned)(base + (int)jr);                            \
            if (c < bb) bb = c;                                              \
        }
        CANDB(pv0.x, pv0.y, B0)
        CANDB(pv0.z, pv0.w, B1)
        CANDB(pv1.x, pv1.y, B2)
        CANDB(pv1.z, pv1.w, B3)
        #undef CANDB
    }
    B0 = dpp_min16(B0); B1 = dpp_min16(B1);
    B2 = dpp_min16(B2); B3 = dpp_min16(B3);

    float sumA = 0.f, sumB = 0.f, sumC = 0.f;
    if (h == 0) {
        // exact reference interp formula for the 4 winners
        #define EPIA(bb, r)                                                  \
        {                                                                    \
            int idx = (int)(unsigned)(bb);                                   \
            int m  = idx / 10;                                               \
            int jj = idx - 10 * m;                                           \
            float s  = s_step[jj];                                           \
            float t  = 1.0f - s;                                             \
            float2 gm = s_gt[m];                                             \
            float2 gp = s_gt[(m + 127) & 127];                               \
            float gx = gm.x * s + gp.x * t;                                  \
            float gy = gm.y * s + gp.y * t;                                  \
            float2 pr = s_pr[4 * g + (r)];                                   \
            sumA += sl1(pr.x - gx) + sl1(pr.y - gy);                         \
        }
        EPIA(B0, 0) EPIA(B1, 1) EPIA(B2, 2) EPIA(B3, 3)
        #undef EPIA
    }

    // ---- Phase C scan: 4 gt points vs strided ini slice {h, h+16, ...} ----
    float4 gv0 = *(const float4*)(&s_gt[4 * g]);       // group-uniform broadcast
    float4 gv1 = *(const float4*)(&s_gt[4 * g + 2]);
    u64 C0 = ~0ull, C1 = ~0ull, C2 = ~0ull, C3 = ~0ull;
    #pragma unroll
    for (int j = 0; j < 8; ++j) {
        const int k = h + 16 * j;
        float2 I = s_ii[k];             // conflict-free
        #define CANDC(gx_, gy_, bb)                                          \
        {                                                                    \
            float dx = I.x - (gx_), dy = I.y - (gy_);                        \
            float d  = fmaf(dy, dy, dx * dx);                                \
            u64 c = ((u64)__builtin_bit_cast(unsigned, d) << 32)             \
                    | (unsigned)k;                                           \
            if (c < bb) bb = c;                                              \
        }
        CANDC(gv0.x, gv0.y, C0)
        CANDC(gv0.z, gv0.w, C1)
        CANDC(gv1.x, gv1.y, C2)
        CANDC(gv1.z, gv1.w, C3)
        #undef CANDC
    }
    C0 = dpp_min16(C0); C1 = dpp_min16(C1);
    C2 = dpp_min16(C2); C3 = dpp_min16(C3);

    if (h == 0) {
        float4 km4 = *(const float4*)(&s_km[4 * g]);
        #define EPIC(bb, gx_, gy_, km_)                                      \
        {                                                                    \
            int k = (int)(unsigned)(bb);                                     \
            float2 pk = s_pr[k];                                             \
            sumB += (km_) * (sl1(pk.x - (gx_)) + sl1(pk.y - (gy_)));         \
            sumC += (km_);                                                   \
        }
        EPIC(C0, gv0.x, gv0.y, km4.x)
        EPIC(C1, gv0.z, gv0.w, km4.y)
        EPIC(C2, gv1.x, gv1.y, km4.z)
        EPIC(C3, gv1.z, gv1.w, km4.w)
        #undef EPIC
        s_sum[0][g] = sumA; s_sum[1][g] = sumB; s_sum[2][g] = sumC;
    }
    __syncthreads();

    if (tid == 0) {
        float A = 0.f, Bs = 0.f, C = 0.f;
        #pragma unroll
        for (int i = 0; i < 32; ++i) {
            A += s_sum[0][i]; Bs += s_sum[1][i]; C += s_sum[2][i];
        }
        partials[b] = make_float4(A, Bs, C, 0.0f);
    }
}

__global__ void __launch_bounds__(256)
dmloss_final(const float4* __restrict__ partials, float* __restrict__ out)
{
    const int tid = threadIdx.x;
    float A = 0.0f, Bs = 0.0f, C = 0.0f;
    #pragma unroll
    for (int i = tid; i < BB; i += 256) {
        float4 p = partials[i];
        A += p.x; Bs += p.y; C += p.z;
    }
    #pragma unroll
    for (int off = 32; off > 0; off >>= 1) {
        A  += __shfl_down(A, off);
        Bs += __shfl_down(Bs, off);
        C  += __shfl_down(C, off);
    }
    __shared__ float sA[4], sB[4], sC[4];
    const int wave = tid >> 6, lane = tid & 63;
    if (lane == 0) { sA[wave] = A; sB[wave] = Bs; sC[wave] = C; }
    __syncthreads();
    if (tid == 0) {
        float a  = sA[0] + sA[1] + sA[2] + sA[3];
        float bs = sB[0] + sB[1] + sB[2] + sB[3];
        float c  = sC[0] + sC[1] + sC[2] + sC[3];
        float loss_pred2gt = a / ((float)BB * (float)NN * 2.0f);
        float loss_set2set = bs / (2.0f * c + 1.0f) + loss_pred2gt;
        out[0] = 0.5f * loss_set2set;
    }
}

extern "C" void kernel_launch(void* const* d_in, const int* in_sizes, int n_in,
                              void* d_out, int out_size, void* d_ws, size_t ws_size,
                              hipStream_t stream)
{
    const float* ini   = (const float*)d_in[0];
    const float* pred  = (const float*)d_in[1];
    const float* gt    = (const float*)d_in[2];
    const float* kmask = (const float*)d_in[3];
    float4* partials = (float4*)d_ws;   // 1024 * 16 B = 16 KiB

    dmloss_main<<<dim3(BB), dim3(512), 0, stream>>>(ini, pred, gt, kmask, partials);
    dmloss_final<<<dim3(1), dim3(256), 0, stream>>>(partials, (float*)d_out);
}

// Round 13
// 19.218 us; speedup vs baseline: 1.0880x; 1.0880x over previous
//
#include <hip/hip_runtime.h>
#include <math.h>

// DMLoss fused kernel for MI355X (gfx950).
// Round 13: packed-pair scan math. R9 skeleton (best, 19.1us) with the two
// owned points' candidate evaluations packed into v2f -> VOP3P v_pk_*_f32
// (2 FLOPs/inst). R1's VALUBusy=63% + instruction audit says the kernel is
// VALU-issue bound with ~2x codegen fat per candidate (addressing, index
// bookkeeping, selects); packing halves the arithmetic stream. Constants come
// from LDS broadcast (R4's readlane failure mode avoided). Merges unchanged.

#define BB 1024
#define NN 128
#define MM 128

typedef float v2f __attribute__((ext_vector_type(2)));

__device__ __forceinline__ float sl1(float x) {
    float d = fabsf(x);
    return d < 1.0f ? 0.5f * d * d : d - 0.5f;
}

__global__ void __launch_bounds__(512, 4)
dmloss_main(const float* __restrict__ ini, const float* __restrict__ pred,
            const float* __restrict__ gt,  const float* __restrict__ kmask,
            float4* __restrict__ partials)
{
    const int b   = blockIdx.x;
    const int tid = threadIdx.x;
    const int g   = tid & 63;    // owns points {2g, 2g+1}
    const int h   = tid >> 6;    // 0..7: scan slice (16 segments / 16 ini points)

    __shared__ __align__(16) float2 s_gt[MM];    // raw gt points
    __shared__ float2 s_pr[NN];                  // pred points (epilogue C gather)
    __shared__ float2 s_ii[NN];                  // ini points (Phase C scan)
    __shared__ float4 s_segA[MM];                // (ax, ay, Xn, Yn)
    __shared__ float2 s_segB[MM];                // (ex/10, ey/10)
    __shared__ float  s_step[16];                // exact j/10
    __shared__ float  s_rv[8 * 128];
    __shared__ float  s_rf[8 * 128];
    __shared__ float  s_sum[3][8];

    const float2* gt2 = (const float2*)(gt   + (size_t)b * MM * 2);
    const float2* in2 = (const float2*)(ini  + (size_t)b * NN * 2);
    const float2* pr2 = (const float2*)(pred + (size_t)b * NN * 2);

    // ---- staging (one barrier) ----
    float2 myPr = make_float2(0.f, 0.f);
    float  myKm = 0.f;
    if (tid < 128) {
        int m = tid;
        float2 gm = gt2[m];
        float2 a  = gt2[(m + 127) & 127];
        s_gt[m] = gm;
        float ex = gm.x - a.x, ey = gm.y - a.y;
        float A  = ex * ex + ey * ey;
        float inv = A > 0.f ? 10.f / A : 0.f;   // degenerate seg -> vertex 0
        s_segA[m] = make_float4(a.x, a.y, -ex * inv, -ey * inv);
        s_segB[m] = make_float2(ex * 0.1f, ey * 0.1f);
        myPr = pr2[m];
        myKm = kmask[b * MM + m];
    } else if (tid < 256) {
        s_pr[tid - 128] = pr2[tid - 128];
    } else if (tid < 384) {
        s_ii[tid - 256] = in2[tid - 256];
    } else if (tid < 400) {
        s_step[tid - 384] = (float)(tid - 384) / 10.0f;
    }

    // Own pred (= ini_pred) points {2g, 2g+1}: one coalesced b128 global load.
    float4 pv = *(const float4*)(&in2[2 * g]);
    const v2f PX = { pv.x, pv.z };
    const v2f PY = { pv.y, pv.w };
    __syncthreads();

    float sumA = 0.f, sumB = 0.f, sumC = 0.f;

    // ---- Phase B: 2 owned pred points vs segment slice [16h, 16h+16) ----
    // Packed over the two points: per segment one v2f candidate pair.
    // jv = qx*Xn + qy*Yn; jr = rint(clamp(jv,0,9)); d = |q + (e/10)*jr|^2.
    float b0 = INFINITY, b1 = INFINITY;
    float f0 = 1e30f, f1 = 1e30f;
    {
        const v2f V0 = { 0.f, 0.f };
        const v2f V9 = { 9.f, 9.f };
        v2f FM = { (float)(160 * h), (float)(160 * h) };
        const v2f T10 = { 10.f, 10.f };
        const int m0 = 16 * h;
        #pragma unroll 2
        for (int j = 0; j < 16; ++j) {
            float4 SA = s_segA[m0 + j];               // broadcast b128
            float2 SB = s_segB[m0 + j];               // broadcast b64
            v2f qx = (v2f){ SA.x, SA.x } - PX;
            v2f qy = (v2f){ SA.y, SA.y } - PY;
            v2f jv = __builtin_elementwise_fma(qy, (v2f){ SA.w, SA.w },
                                               qx * (v2f){ SA.z, SA.z });
            v2f jc = __builtin_elementwise_min(
                         __builtin_elementwise_max(jv, V0), V9);
            v2f jr = __builtin_elementwise_rint(jc);
            v2f dx = __builtin_elementwise_fma(jr, (v2f){ SB.x, SB.x }, qx);
            v2f dy = __builtin_elementwise_fma(jr, (v2f){ SB.y, SB.y }, qy);
            v2f d  = __builtin_elementwise_fma(dy, dy, dx * dx);
            v2f fi = jr + FM;
            if (d.x < b0) { b0 = d.x; f0 = fi.x; }    // ascending -> first occ.
            if (d.y < b1) { b1 = d.y; f1 = fi.y; }
            FM = FM + T10;
        }
    }
    {
        float2* rv2 = (float2*)&s_rv[h * 128 + 2 * g];
        float2* rf2 = (float2*)&s_rf[h * 128 + 2 * g];
        *rv2 = make_float2(b0, b1);
        *rf2 = make_float2(f0, f1);
    }
    __syncthreads();

    // merge 8 slices per point + exact epilogue A
    if (tid < 128) {
        float best = s_rv[tid], bf = s_rf[tid];
        #pragma unroll
        for (int q = 1; q < 8; ++q) {
            float ov = s_rv[q * 128 + tid];
            float of = s_rf[q * 128 + tid];
            if (ov < best || (ov == best && of < bf)) { best = ov; bf = of; }
        }
        int bidx = (int)bf;
        int m = bidx / 10;
        int j = bidx - m * 10;
        float s  = s_step[j];
        float tt = 1.0f - s;
        float2 gm = s_gt[m];
        float2 gp = s_gt[(m + 127) & 127];
        float gx = gm.x * s + gp.x * tt;   // exact reference interp formula
        float gy = gm.y * s + gp.y * tt;
        sumA = sl1(myPr.x - gx) + sl1(myPr.y - gy);
    }
    __syncthreads();   // protect s_rv/s_rf reuse

    // ---- Phase C: 2 owned gt points vs ini slice [16h, 16h+16) ----
    {
        float4 gv = *(const float4*)(&s_gt[2 * g]);
        const v2f GX = { gv.x, gv.z };
        const v2f GY = { gv.y, gv.w };
        b0 = INFINITY; b1 = INFINITY;
        f0 = 1e30f; f1 = 1e30f;
        v2f FK = { (float)(16 * h), (float)(16 * h) };
        const v2f T1 = { 1.f, 1.f };
        const int k0 = 16 * h;
        #pragma unroll 4
        for (int j = 0; j < 16; ++j) {
            float2 I = s_ii[k0 + j];                  // broadcast b64
            v2f dx = (v2f){ I.x, I.x } - GX;
            v2f dy = (v2f){ I.y, I.y } - GY;
            v2f d  = __builtin_elementwise_fma(dy, dy, dx * dx);
            if (d.x < b0) { b0 = d.x; f0 = FK.x; }
            if (d.y < b1) { b1 = d.y; f1 = FK.y; }
            FK = FK + T1;
        }
        float2* rv2 = (float2*)&s_rv[h * 128 + 2 * g];
        float2* rf2 = (float2*)&s_rf[h * 128 + 2 * g];
        *rv2 = make_float2(b0, b1);
        *rf2 = make_float2(f0, f1);
    }
    __syncthreads();

    if (tid < 128) {
        float best = s_rv[tid], bf = s_rf[tid];
        #pragma unroll
        for (int q = 1; q < 8; ++q) {
            float ov = s_rv[q * 128 + tid];
            float of = s_rf[q * 128 + tid];
            if (ov < best || (ov == best && of < bf)) { best = ov; bf = of; }
        }
        int k = (int)bf;
        float2 pk2 = s_pr[k];
        float2 g0  = s_gt[tid];
        sumB = myKm * (sl1(pk2.x - g0.x) + sl1(pk2.y - g0.y));
        sumC = myKm;
    }

    // ---- Block reduction of (sumA, sumB, sumC) ----
    #pragma unroll
    for (int off = 32; off > 0; off >>= 1) {
        sumA += __shfl_down(sumA, off);
        sumB += __shfl_down(sumB, off);
        sumC += __shfl_down(sumC, off);
    }
    const int wave = tid >> 6;
    if ((tid & 63) == 0) {
        s_sum[0][wave] = sumA; s_sum[1][wave] = sumB; s_sum[2][wave] = sumC;
    }
    __syncthreads();
    if (tid == 0) {
        float A = 0.f, Bs = 0.f, C = 0.f;
        #pragma unroll
        for (int w = 0; w < 8; ++w) {
            A += s_sum[0][w]; Bs += s_sum[1][w]; C += s_sum[2][w];
        }
        partials[b] = make_float4(A, Bs, C, 0.0f);
    }
}

__global__ void __launch_bounds__(256)
dmloss_final(const float4* __restrict__ partials, float* __restrict__ out)
{
    const int tid = threadIdx.x;
    float A = 0.0f, Bs = 0.0f, C = 0.0f;
    #pragma unroll
    for (int i = tid; i < BB; i += 256) {
        float4 p = partials[i];
        A += p.x; Bs += p.y; C += p.z;
    }
    #pragma unroll
    for (int off = 32; off > 0; off >>= 1) {
        A  += __shfl_down(A, off);
        Bs += __shfl_down(Bs, off);
        C  += __shfl_down(C, off);
    }
    __shared__ float sA[4], sB[4], sC[4];
    const int wave = tid >> 6, lane = tid & 63;
    if (lane == 0) { sA[wave] = A; sB[wave] = Bs; sC[wave] = C; }
    __syncthreads();
    if (tid == 0) {
        float a  = sA[0] + sA[1] + sA[2] + sA[3];
        float bs = sB[0] + sB[1] + sB[2] + sB[3];
        float c  = sC[0] + sC[1] + sC[2] + sC[3];
        float loss_pred2gt = a / ((float)BB * (float)NN * 2.0f);
        float loss_set2set = bs / (2.0f * c + 1.0f) + loss_pred2gt;
        out[0] = 0.5f * loss_set2set;
    }
}

extern "C" void kernel_launch(void* const* d_in, const int* in_sizes, int n_in,
                              void* d_out, int out_size, void* d_ws, size_t ws_size,
                              hipStream_t stream)
{
    const float* ini   = (const float*)d_in[0];
    const float* pred  = (const float*)d_in[1];
    const float* gt    = (const float*)d_in[2];
    const float* kmask = (const float*)d_in[3];
    float4* partials = (float4*)d_ws;   // 1024 * 16 B = 16 KiB

    dmloss_main<<<dim3(BB), dim3(512), 0, stream>>>(ini, pred, gt, kmask, partials);
    dmloss_final<<<dim3(1), dim3(256), 0, stream>>>(partials, (float*)d_out);
}

// Round 14
// 18.082 us; speedup vs baseline: 1.1564x; 1.0628x over previous
//
#include <hip/hip_runtime.h>
#include <math.h>

// DMLoss fused kernel for MI355X (gfx950).
// Round 14: block-granularity isolation. Same scan math as R9 (best, 19.1us)
// reshaped to 256-thread blocks x 2048 blocks: 8 blocks/CU x 4 waves = same
// 32 waves/CU occupancy, but barriers couple 4 waves instead of 8, merge
// idles are shorter, and 8 independent blocks/CU overlap merges with scans.
// Block = (batch b, half): owns 64 points (P=1), 4-way scan split
// (h = tid>>6, 32 segments/slice). __launch_bounds__(256,8) -> 64-VGPR cap;
// P=1 loop is well under (R7/R8 P=2 fit without spills).

#define BB 1024
#define NN 128
#define MM 128

__device__ __forceinline__ float sl1(float x) {
    float d = fabsf(x);
    return d < 1.0f ? 0.5f * d * d : d - 0.5f;
}

__global__ void __launch_bounds__(256, 8)
dmloss_main(const float* __restrict__ ini, const float* __restrict__ pred,
            const float* __restrict__ gt,  const float* __restrict__ kmask,
            float4* __restrict__ partials)
{
    const int b    = blockIdx.x >> 1;
    const int half = blockIdx.x & 1;      // owns points [64*half, 64*half+64)
    const int tid  = threadIdx.x;
    const int g    = tid & 63;            // owned point: P = 64*half + g
    const int h    = tid >> 6;            // 0..3: scan slice (32 segs / 32 ini)
    const int P    = (half << 6) + g;

    __shared__ __align__(16) float2 s_gt[MM];
    __shared__ float2 s_pr[NN];
    __shared__ float2 s_ii[NN];
    __shared__ float4 s_segA[MM];                // (ax, ay, Xn, Yn)
    __shared__ float2 s_segB[MM];                // (ex/10, ey/10)
    __shared__ float  s_step[16];                // exact j/10
    __shared__ float  s_rv[4 * 64];
    __shared__ float  s_rf[4 * 64];
    __shared__ float  s_sum[3][4];

    const float2* gt2 = (const float2*)(gt   + (size_t)b * MM * 2);
    const float2* in2 = (const float2*)(ini  + (size_t)b * NN * 2);
    const float2* pr2 = (const float2*)(pred + (size_t)b * NN * 2);

    // ---- staging (one barrier): 256 threads cover 128 segs + 128 pr/ii ----
    if (tid < 128) {
        int m = tid;
        float2 gm = gt2[m];
        float2 a  = gt2[(m + 127) & 127];
        s_gt[m] = gm;
        float ex = gm.x - a.x, ey = gm.y - a.y;
        float A  = ex * ex + ey * ey;
        float inv = A > 0.f ? 10.f / A : 0.f;   // degenerate seg -> vertex 0
        s_segA[m] = make_float4(a.x, a.y, -ex * inv, -ey * inv);
        s_segB[m] = make_float2(ex * 0.1f, ey * 0.1f);
        if (tid < 16) s_step[tid] = (float)tid / 10.0f;
    } else {
        int k = tid - 128;
        s_pr[k] = pr2[k];
        s_ii[k] = in2[k];
    }
    // Own point data (register-resident; coalesced within each wave).
    float2 myP  = in2[P];                  // ini_pred point (scanned against segs)
    float2 myPr = pr2[P];                  // pred point (epilogue A)
    float2 myG  = gt2[P];                  // gt point (Phase C owner)
    float  myKm = kmask[b * MM + P];       // mask (epilogue C)
    const float px = myP.x, py = myP.y;
    __syncthreads();

    float sumA = 0.f, sumB = 0.f, sumC = 0.f;

    // ---- Phase B: owned pred point vs segment slice [32h, 32h+32) ----
    // jv = qx*Xn + qy*Yn (q = a - p); jr = rint(med3(jv,0,9));
    // d = |q + (e/10)*jr|^2; fi = 10*m + jr.
    float b0 = INFINITY, f0 = 1e30f;
    {
        float fm = (float)(320 * h);
        const int m0 = 32 * h;
        #pragma unroll 4
        for (int j = 0; j < 32; ++j) {
            float4 SA = s_segA[m0 + j];               // wave-uniform broadcast
            float2 SB = s_segB[m0 + j];
            float qx = SA.x - px, qy = SA.y - py;
            float jv = fmaf(qy, SA.w, qx * SA.z);
            float jr = rintf(__builtin_amdgcn_fmed3f(jv, 0.f, 9.f));
            float dx = fmaf(jr, SB.x, qx);
            float dy = fmaf(jr, SB.y, qy);
            float d  = fmaf(dy, dy, dx * dx);
            float fi = fm + jr;
            if (d < b0) { b0 = d; f0 = fi; }          // ascending -> first occ.
            fm += 10.f;
        }
    }
    s_rv[h * 64 + g] = b0;
    s_rf[h * 64 + g] = f0;
    __syncthreads();

    // merge 4 slices (64 active threads) + exact epilogue A
    if (tid < 64) {
        float best = s_rv[tid], bf = s_rf[tid];
        #pragma unroll
        for (int q = 1; q < 4; ++q) {
            float ov = s_rv[q * 64 + tid];
            float of = s_rf[q * 64 + tid];
            if (ov < best || (ov == best && of < bf)) { best = ov; bf = of; }
        }
        int bidx = (int)bf;
        int m = bidx / 10;
        int j = bidx - m * 10;
        float s  = s_step[j];
        float tt = 1.0f - s;
        float2 gm = s_gt[m];
        float2 gp = s_gt[(m + 127) & 127];
        float gx = gm.x * s + gp.x * tt;   // exact reference interp formula
        float gy = gm.y * s + gp.y * tt;
        float2 pr = s_pr[(half << 6) + tid];
        sumA = sl1(pr.x - gx) + sl1(pr.y - gy);
    }
    __syncthreads();   // protect s_rv/s_rf reuse

    // ---- Phase C: owned gt point vs ini slice [32h, 32h+32) ----
    {
        const float gx = myG.x, gy = myG.y;
        b0 = INFINITY; f0 = 1e30f;
        float fk = (float)(32 * h);
        const int k0 = 32 * h;
        #pragma unroll 4
        for (int j = 0; j < 32; ++j) {
            float2 I = s_ii[k0 + j];                  // wave-uniform broadcast
            float dx = I.x - gx, dy = I.y - gy;
            float d  = fmaf(dy, dy, dx * dx);
            if (d < b0) { b0 = d; f0 = fk; }
            fk += 1.f;
        }
        s_rv[h * 64 + g] = b0;
        s_rf[h * 64 + g] = f0;
    }
    __syncthreads();

    if (tid < 64) {
        float best = s_rv[tid], bf = s_rf[tid];
        #pragma unroll
        for (int q = 1; q < 4; ++q) {
            float ov = s_rv[q * 64 + tid];
            float of = s_rf[q * 64 + tid];
            if (ov < best || (ov == best && of < bf)) { best = ov; bf = of; }
        }
        int k = (int)bf;
        float2 pk2 = s_pr[k];
        float2 g0  = s_gt[(half << 6) + tid];
        float  km  = kmask[b * MM + (half << 6) + tid];
        sumB = km * (sl1(pk2.x - g0.x) + sl1(pk2.y - g0.y));
        sumC = km;
    }

    // ---- Block reduction ----
    #pragma unroll
    for (int off = 32; off > 0; off >>= 1) {
        sumA += __shfl_down(sumA, off);
        sumB += __shfl_down(sumB, off);
        sumC += __shfl_down(sumC, off);
    }
    const int wave = tid >> 6;
    if ((tid & 63) == 0) {
        s_sum[0][wave] = sumA; s_sum[1][wave] = sumB; s_sum[2][wave] = sumC;
    }
    __syncthreads();
    if (tid == 0) {
        float A = 0.f, Bs = 0.f, C = 0.f;
        #pragma unroll
        for (int w = 0; w < 4; ++w) {
            A += s_sum[0][w]; Bs += s_sum[1][w]; C += s_sum[2][w];
        }
        partials[blockIdx.x] = make_float4(A, Bs, C, 0.0f);
    }
}

__global__ void __launch_bounds__(256)
dmloss_final(const float4* __restrict__ partials, float* __restrict__ out)
{
    const int tid = threadIdx.x;
    float A = 0.0f, Bs = 0.0f, C = 0.0f;
    #pragma unroll
    for (int i = tid; i < 2 * BB; i += 256) {
        float4 p = partials[i];
        A += p.x; Bs += p.y; C += p.z;
    }
    #pragma unroll
    for (int off = 32; off > 0; off >>= 1) {
        A  += __shfl_down(A, off);
        Bs += __shfl_down(Bs, off);
        C  += __shfl_down(C, off);
    }
    __shared__ float sA[4], sB[4], sC[4];
    const int wave = tid >> 6, lane = tid & 63;
    if (lane == 0) { sA[wave] = A; sB[wave] = Bs; sC[wave] = C; }
    __syncthreads();
    if (tid == 0) {
        float a  = sA[0] + sA[1] + sA[2] + sA[3];
        float bs = sB[0] + sB[1] + sB[2] + sB[3];
        float c  = sC[0] + sC[1] + sC[2] + sC[3];
        float loss_pred2gt = a / ((float)BB * (float)NN * 2.0f);
        float loss_set2set = bs / (2.0f * c + 1.0f) + loss_pred2gt;
        out[0] = 0.5f * loss_set2set;
    }
}

extern "C" void kernel_launch(void* const* d_in, const int* in_sizes, int n_in,
                              void* d_out, int out_size, void* d_ws, size_t ws_size,
                              hipStream_t stream)
{
    const float* ini   = (const float*)d_in[0];
    const float* pred  = (const float*)d_in[1];
    const float* gt    = (const float*)d_in[2];
    const float* kmask = (const float*)d_in[3];
    float4* partials = (float4*)d_ws;   // 2048 * 16 B = 32 KiB

    dmloss_main<<<dim3(2 * BB), dim3(256), 0, stream>>>(ini, pred, gt, kmask, partials);
    dmloss_final<<<dim3(1), dim3(256), 0, stream>>>(partials, (float*)d_out);
}